// Round 4
// baseline (269.584 us; speedup 1.0000x reference)
//
#include <hip/hip_runtime.h>
#include <cstdint>
#include <cstddef>

typedef __attribute__((ext_vector_type(8))) __bf16 bf16x8;
typedef __attribute__((ext_vector_type(4))) float f32x4;
typedef __attribute__((ext_vector_type(8))) unsigned short u16x8;

__device__ __forceinline__ unsigned short f2bf(float f) {
  union { float f; unsigned u; } v; v.f = f;
  unsigned u = v.u;
  return (unsigned short)((u + 0x7FFFu + ((u >> 16) & 1u)) >> 16);
}

__device__ __forceinline__ void async16(const void* g, void* l) {
  __builtin_amdgcn_global_load_lds(
      (const __attribute__((address_space(1))) unsigned int*)g,
      (__attribute__((address_space(3))) unsigned int*)l, 16, 0, 0);
}

// ---------------- prologue 1: x fp32 -> bf16 ----------------
__global__ __launch_bounds__(256) void cvt_x_kern(const float* __restrict__ x,
                                                  unsigned short* __restrict__ xb) {
  int idx = blockIdx.x * 256 + threadIdx.x;
  const float4* src = (const float4*)x + (size_t)idx * 2;
  float4 a = src[0], b = src[1];
  u16x8 v;
  v[0] = f2bf(a.x); v[1] = f2bf(a.y); v[2] = f2bf(a.z); v[3] = f2bf(a.w);
  v[4] = f2bf(b.x); v[5] = f2bf(b.y); v[6] = f2bf(b.z); v[7] = f2bf(b.w);
  *((u16x8*)xb + idx) = v;
}

// ---------------- prologue 2: expand W -> M (stored [N][K] bf16) ----------------
__global__ __launch_bounds__(64) void expand_w_kern(const float* __restrict__ W,
                                                    unsigned short* __restrict__ Mb) {
  int i = blockIdx.x >> 6, j = blockIdx.x & 63;
  int c = threadIdx.x;
  __shared__ unsigned short w16[64];
  w16[c] = f2bf(W[((size_t)(i * 64 + j)) * 64 + c]);
  __syncthreads();
  unsigned short* dst = Mb + (size_t)(i * 64 + c) * 4096 + j * 64;
#pragma unroll
  for (int g = 0; g < 8; ++g) {
    u16x8 v;
#pragma unroll
    for (int e = 0; e < 8; ++e) v[e] = w16[(c - (g * 8 + e)) & 63];
    *(u16x8*)(dst + g * 8) = v;
  }
}

// ---------------- main GEMM: 256x256, BK=64, read-ahead 4-phase schedule ----------------
// Quad order (0,0),(0,1),(1,1),(1,0).  Reads: P0 bL+bH(8) / P1 aH(8, ahead) /
// P2 next-tile aL(8, ahead, after vmcnt(4)+bar) / P3 none.  Boundary vmcnt(4)
// folded before P3's trailing barrier -> 7 barriers/tile.  LDS slot^(row&7)
// swizzle on both global-source and ds_read sides (linear LDS dest).
#define FE asm volatile("" ::: "memory")
#define BARRIER() do { FE; __builtin_amdgcn_s_barrier(); FE; } while (0)

#define MFQ(AF, MB, BF, NB)                                                      \
  __builtin_amdgcn_s_setprio(1);                                                 \
  _Pragma("unroll") for (int ks = 0; ks < 2; ++ks)                               \
      _Pragma("unroll") for (int mi = 0; mi < 4; ++mi)                           \
      _Pragma("unroll") for (int ni = 0; ni < 2; ++ni)                           \
      acc[(MB) + mi][(NB) + ni] = __builtin_amdgcn_mfma_f32_16x16x32_bf16(       \
          AF[mi][ks], BF[ni][ks], acc[(MB) + mi][(NB) + ni], 0, 0, 0);           \
  __builtin_amdgcn_s_setprio(0);

// MODE: 0 steady, 1 = tt==62 (no t+2 stage, boundary vmcnt(0)), 2 = tt==63 (final)
#define TILE_BODY(TT, CUR, MODE)                                                 \
  do {                                                                           \
    const char* pa = lds + (CUR) * 65536 + wm * 128;                             \
    const char* pb = lds + (CUR) * 65536 + 32768 + wn * 128;                     \
    const char* pan = lds + ((CUR) ^ 1) * 65536 + wm * 128;                      \
    bf16x8 a1[4][2], bl[2][2], bh[2][2];                                         \
    /* ---- P0: read bL,bH; stage t+1 B0; MFMA (0,0) ---- */                     \
    _Pragma("unroll") for (int ni = 0; ni < 2; ++ni)                             \
        _Pragma("unroll") for (int ks = 0; ks < 2; ++ks)                         \
        bl[ni][ks] = *(const bf16x8*)(pb + koff[ks] + ni * 2048);                \
    _Pragma("unroll") for (int ni = 0; ni < 2; ++ni)                             \
        _Pragma("unroll") for (int ks = 0; ks < 2; ++ks)                         \
        bh[ni][ks] = *(const bf16x8*)(pb + koff[ks] + (2 + ni) * 2048);          \
    if ((MODE) < 2) stage((TT) + 1, 2);                                          \
    BARRIER();                                                                   \
    MFQ(a0, 0, bl, 0)                                                            \
    BARRIER();                                                                   \
    /* ---- P1: read aH (ahead); stage t+1 B1; MFMA (0,1) ---- */                \
    _Pragma("unroll") for (int mi = 0; mi < 4; ++mi)                             \
        _Pragma("unroll") for (int ks = 0; ks < 2; ++ks)                         \
        a1[mi][ks] = *(const bf16x8*)(pa + koff[ks] + (4 + mi) * 2048);          \
    if ((MODE) < 2) stage((TT) + 1, 3);                                          \
    BARRIER();                                                                   \
    MFQ(a0, 0, bh, 2)                                                            \
    BARRIER();                                                                   \
    /* ---- P2: vmcnt(4) legalizes next-tile A; refill a0; MFMA (1,1) ---- */    \
    if ((MODE) < 2) asm volatile("s_waitcnt vmcnt(4)" ::: "memory");             \
    BARRIER();                                                                   \
    if ((MODE) < 2) {                                                            \
      _Pragma("unroll") for (int mi = 0; mi < 4; ++mi)                           \
          _Pragma("unroll") for (int ks = 0; ks < 2; ++ks)                       \
          a0[mi][ks] = *(const bf16x8*)(pan + koff[ks] + mi * 2048);             \
    }                                                                            \
    MFQ(a1, 4, bh, 2)                                                            \
    BARRIER();                                                                   \
    /* ---- P3: stage t+2 A; MFMA (1,0); boundary vmcnt before barrier ---- */   \
    if ((MODE) == 0) {                                                           \
      stage((TT) + 2, 0);                                                        \
      stage((TT) + 2, 1);                                                        \
    }                                                                            \
    MFQ(a1, 4, bl, 0)                                                            \
    if ((MODE) == 0)                                                             \
      asm volatile("s_waitcnt vmcnt(4)" ::: "memory");                           \
    else if ((MODE) == 1)                                                        \
      asm volatile("s_waitcnt vmcnt(0)" ::: "memory");                           \
    if ((MODE) < 2) BARRIER();                                                   \
  } while (0)

__global__ __launch_bounds__(512, 2) void gemm8(const unsigned short* __restrict__ A,
                                                const unsigned short* __restrict__ B,
                                                float* __restrict__ C) {
  __shared__ __align__(16) char lds[131072];
  int bid = blockIdx.x;
  int swz = (bid & 7) * 32 + (bid >> 3);  // bijective: 256 = 8*32
  int bm = swz >> 4, bn = swz & 15;
  int t = threadIdx.x;
  int w = t >> 6, l = t & 63;
  int wm = (w >> 2) * 128;  // 2 M-groups
  int wn = (w & 3) * 64;    // 4 N-groups

  f32x4 acc[8][4];
#pragma unroll
  for (int a_ = 0; a_ < 8; ++a_)
#pragma unroll
    for (int b_ = 0; b_ < 4; ++b_) acc[a_][b_] = (f32x4){0.f, 0.f, 0.f, 0.f};

  const int rowin = w * 8 + (l >> 3);    // staging row within 64-row group
  const int cslot = (l & 7) ^ (l >> 3);  // pre-swizzled global k-slot
  int koff[2];
#pragma unroll
  for (int ks = 0; ks < 2; ++ks)
    koff[ks] = (l & 15) * 128 + ((ks * 4 + (l >> 4)) ^ (l & 7)) * 16;

  const size_t abase = (size_t)bm * 256 * 4096;
  const size_t bbase = (size_t)bn * 256 * 4096;

  auto stage = [&](int kt, int c) {
    const unsigned short* mat = (c < 2) ? A : B;
    size_t gbase = (c < 2) ? abase : bbase;
    int half = c & 1;
    char* ldst = lds + (kt & 1) * 65536 + ((c < 2) ? 0 : 32768) + half * 16384 + w * 1024;
#pragma unroll
    for (int i = 0; i < 2; ++i) {
      int r = half * 128 + i * 64 + rowin;
      async16(mat + gbase + (size_t)r * 4096 + kt * 64 + cslot * 8, ldst + i * 8192);
    }
  };

  // prologue: tile 0 fully, tile 1 A-halves; then pre-read tile 0's A-low
#pragma unroll
  for (int c = 0; c < 4; ++c) stage(0, c);
  stage(1, 0);
  stage(1, 1);
  asm volatile("s_waitcnt vmcnt(4)" ::: "memory");
  BARRIER();

  bf16x8 a0[4][2];
#pragma unroll
  for (int mi = 0; mi < 4; ++mi)
#pragma unroll
    for (int ks = 0; ks < 2; ++ks)
      a0[mi][ks] = *(const bf16x8*)(lds + wm * 128 + koff[ks] + mi * 2048);

  for (int tt = 0; tt < 62; tt += 2) {
    TILE_BODY(tt, 0, 0);
    TILE_BODY(tt + 1, 1, 0);
  }
  TILE_BODY(62, 0, 1);
  TILE_BODY(63, 1, 2);

#undef TILE_BODY
#undef MFQ

  // C/D layout (m89-verified): col = lane&15, row = (lane>>4)*4 + reg
  int r0 = (l >> 4) * 4;
#pragma unroll
  for (int mi = 0; mi < 8; ++mi) {
    size_t row = (size_t)(bm * 256 + wm + mi * 16 + r0);
#pragma unroll
    for (int ni = 0; ni < 4; ++ni) {
      int col = bn * 256 + wn + ni * 16 + (l & 15);
#pragma unroll
      for (int r = 0; r < 4; ++r)
        C[(row + r) * 4096 + col] = acc[mi][ni][r];
    }
  }
}

// ---------------- fallback (no workspace): fp32 register-blocked ----------------
__global__ __launch_bounds__(256) void fallback_kern(const float* __restrict__ x,
                                                     const float* __restrict__ W,
                                                     float* __restrict__ out) {
  int bi = blockIdx.x & 63;
  int bb = blockIdx.x >> 6;
  int t = threadIdx.x;
  int m = t & 63;
  int cg = t >> 6;
  __shared__ float xs[64][65];
  __shared__ float ws[64];
  float acc[16];
#pragma unroll
  for (int e = 0; e < 16; ++e) acc[e] = 0.f;
  for (int j = 0; j < 64; ++j) {
    __syncthreads();
#pragma unroll
    for (int r = 0; r < 16; ++r) {
      int idx = t + 256 * r;
      int rr = idx >> 6, cc = idx & 63;
      xs[rr][cc] = x[(size_t)(bb * 64 + rr) * 4096 + j * 64 + cc];
    }
    if (t < 64) ws[t] = W[((size_t)(bi * 64 + j)) * 64 + t];
    __syncthreads();
    float xr[64];
#pragma unroll
    for (int e = 0; e < 64; ++e) xr[e] = xs[m][(cg * 16 + e) & 63];
#pragma unroll
    for (int mm = 0; mm < 64; ++mm) {
      float wv = ws[mm];
#pragma unroll
      for (int cc2 = 0; cc2 < 16; ++cc2)
        acc[cc2] = __builtin_fmaf(xr[(cc2 - mm) & 63], wv, acc[cc2]);
    }
  }
  float* dst = out + (size_t)(bb * 64 + m) * 4096 + bi * 64 + cg * 16;
#pragma unroll
  for (int cc2 = 0; cc2 < 16; ++cc2) dst[cc2] = acc[cc2];
}

extern "C" void kernel_launch(void* const* d_in, const int* in_sizes, int n_in,
                              void* d_out, int out_size, void* d_ws, size_t ws_size,
                              hipStream_t stream) {
  const float* x = (const float*)d_in[0];
  const float* W = (const float*)d_in[1];
  float* out = (float*)d_out;
  const size_t need = (size_t)2 * 4096 * 4096 * sizeof(unsigned short);  // 64 MB
  if (ws_size >= need) {
    unsigned short* xb = (unsigned short*)d_ws;
    unsigned short* Mb = xb + (size_t)4096 * 4096;
    cvt_x_kern<<<dim3(8192), dim3(256), 0, stream>>>(x, xb);
    expand_w_kern<<<dim3(4096), dim3(64), 0, stream>>>(W, Mb);
    gemm8<<<dim3(256), dim3(512), 0, stream>>>(xb, Mb, out);
  } else {
    fallback_kern<<<dim3(4096), dim3(256), 0, stream>>>(x, W, out);
  }
}

// Round 5
// 144.126 us; speedup vs baseline: 1.8705x; 1.8705x over previous
//
#include <hip/hip_runtime.h>
#include <cstdint>
#include <cstddef>

typedef __attribute__((ext_vector_type(8))) __bf16 bf16x8;
typedef __attribute__((ext_vector_type(4))) float f32x4;
typedef __attribute__((ext_vector_type(8))) unsigned short u16x8;

__device__ __forceinline__ unsigned short f2bf(float f) {
  union { float f; unsigned u; } v; v.f = f;
  unsigned u = v.u;
  return (unsigned short)((u + 0x7FFFu + ((u >> 16) & 1u)) >> 16);
}

__device__ __forceinline__ void async16(const void* g, void* l) {
  __builtin_amdgcn_global_load_lds(
      (const __attribute__((address_space(1))) unsigned int*)g,
      (__attribute__((address_space(3))) unsigned int*)l, 16, 0, 0);
}

// ---------------- prologue 1: x fp32 -> bf16 ----------------
__global__ __launch_bounds__(256) void cvt_x_kern(const float* __restrict__ x,
                                                  unsigned short* __restrict__ xb) {
  int idx = blockIdx.x * 256 + threadIdx.x;
  const float4* src = (const float4*)x + (size_t)idx * 2;
  float4 a = src[0], b = src[1];
  u16x8 v;
  v[0] = f2bf(a.x); v[1] = f2bf(a.y); v[2] = f2bf(a.z); v[3] = f2bf(a.w);
  v[4] = f2bf(b.x); v[5] = f2bf(b.y); v[6] = f2bf(b.z); v[7] = f2bf(b.w);
  *((u16x8*)xb + idx) = v;
}

// ---------------- prologue 2: expand W -> M (stored [N][K] bf16) ----------------
__global__ __launch_bounds__(64) void expand_w_kern(const float* __restrict__ W,
                                                    unsigned short* __restrict__ Mb) {
  int i = blockIdx.x >> 6, j = blockIdx.x & 63;
  int c = threadIdx.x;
  __shared__ unsigned short w16[64];
  w16[c] = f2bf(W[((size_t)(i * 64 + j)) * 64 + c]);
  __syncthreads();
  unsigned short* dst = Mb + (size_t)(i * 64 + c) * 4096 + j * 64;
#pragma unroll
  for (int g = 0; g < 8; ++g) {
    u16x8 v;
#pragma unroll
    for (int e = 0; e < 8; ++e) v[e] = w16[(c - (g * 8 + e)) & 63];
    *(u16x8*)(dst + g * 8) = v;
  }
}

// ---------------- main GEMM: 256x256, BK=64, deep-prefetch 4-phase schedule ----------------
// Round-3 phase structure (all fragments tile-local -> no spill), plus:
//  * tile t+2's B staged in P2, A staged in P3 (both regions of buf[cur] fully
//    read by then) -> boundary vmcnt(8) waits on loads issued a FULL tile ago.
//  * P3 merged: stage + reg-only MFMA + vmcnt + ONE barrier (7 barriers/tile).
//  * no explicit lgkmcnt(0): compiler emits counted lgkm waits per MFMA operand.
#define FE asm volatile("" ::: "memory")
#define BARRIER() do { FE; __builtin_amdgcn_s_barrier(); FE; } while (0)

#define MFQ(AF, MB, BF, NB)                                                      \
  __builtin_amdgcn_s_setprio(1);                                                 \
  _Pragma("unroll") for (int ks = 0; ks < 2; ++ks)                               \
      _Pragma("unroll") for (int mi = 0; mi < 4; ++mi)                           \
      _Pragma("unroll") for (int ni = 0; ni < 2; ++ni)                           \
      acc[(MB) + mi][(NB) + ni] = __builtin_amdgcn_mfma_f32_16x16x32_bf16(       \
          AF[mi][ks], BF[ni][ks], acc[(MB) + mi][(NB) + ni], 0, 0, 0);           \
  __builtin_amdgcn_s_setprio(0);

// MODE: 0 steady, 1 = tt==62 (no stages, boundary vmcnt(0)), 2 = tt==63 (final)
#define TILE_BODY(TT, CUR, MODE)                                                 \
  do {                                                                           \
    const char* pa = lds + (CUR) * 65536 + wm * 128;                             \
    const char* pb = lds + (CUR) * 65536 + 32768 + wn * 128;                     \
    bf16x8 a0[4][2], a1[4][2], bl[2][2], bh[2][2];                               \
    /* ---- P0: read aL(8)+bL(4); MFMA (0,0) ---- */                             \
    _Pragma("unroll") for (int mi = 0; mi < 4; ++mi)                             \
        _Pragma("unroll") for (int ks = 0; ks < 2; ++ks)                         \
        a0[mi][ks] = *(const bf16x8*)(pa + koff[ks] + mi * 2048);                \
    _Pragma("unroll") for (int ni = 0; ni < 2; ++ni)                             \
        _Pragma("unroll") for (int ks = 0; ks < 2; ++ks)                         \
        bl[ni][ks] = *(const bf16x8*)(pb + koff[ks] + ni * 2048);                \
    BARRIER();                                                                   \
    MFQ(a0, 0, bl, 0)                                                            \
    BARRIER();                                                                   \
    /* ---- P1: read bH(4); MFMA (0,1) ---- */                                   \
    _Pragma("unroll") for (int ni = 0; ni < 2; ++ni)                             \
        _Pragma("unroll") for (int ks = 0; ks < 2; ++ks)                         \
        bh[ni][ks] = *(const bf16x8*)(pb + koff[ks] + (2 + ni) * 2048);          \
    BARRIER();                                                                   \
    MFQ(a0, 0, bh, 2)                                                            \
    BARRIER();                                                                   \
    /* ---- P2: read aH(8); stage t+2 B (region free after P1 bar); MFMA (1,1) */\
    _Pragma("unroll") for (int mi = 0; mi < 4; ++mi)                             \
        _Pragma("unroll") for (int ks = 0; ks < 2; ++ks)                         \
        a1[mi][ks] = *(const bf16x8*)(pa + koff[ks] + (4 + mi) * 2048);          \
    if ((MODE) == 0) {                                                           \
      stage((TT) + 2, 2);                                                        \
      stage((TT) + 2, 3);                                                        \
    }                                                                            \
    BARRIER();                                                                   \
    MFQ(a1, 4, bh, 2)                                                            \
    BARRIER();                                                                   \
    /* ---- P3: stage t+2 A; reg-only MFMA (1,0); boundary vmcnt + 1 barrier */  \
    if ((MODE) == 0) {                                                           \
      stage((TT) + 2, 0);                                                        \
      stage((TT) + 2, 1);                                                        \
    }                                                                            \
    MFQ(a1, 4, bl, 0)                                                            \
    if ((MODE) == 0)                                                             \
      asm volatile("s_waitcnt vmcnt(8)" ::: "memory");                           \
    else if ((MODE) == 1)                                                        \
      asm volatile("s_waitcnt vmcnt(0)" ::: "memory");                           \
    if ((MODE) < 2) BARRIER();                                                   \
  } while (0)

__global__ __launch_bounds__(512, 2) void gemm8(const unsigned short* __restrict__ A,
                                                const unsigned short* __restrict__ B,
                                                float* __restrict__ C) {
  __shared__ __align__(16) char lds[131072];
  int bid = blockIdx.x;
  int swz = (bid & 7) * 32 + (bid >> 3);  // bijective: 256 = 8*32
  int bm = swz >> 4, bn = swz & 15;
  int t = threadIdx.x;
  int w = t >> 6, l = t & 63;
  int wm = (w >> 2) * 128;  // 2 M-groups
  int wn = (w & 3) * 64;    // 4 N-groups

  f32x4 acc[8][4];
#pragma unroll
  for (int a_ = 0; a_ < 8; ++a_)
#pragma unroll
    for (int b_ = 0; b_ < 4; ++b_) acc[a_][b_] = (f32x4){0.f, 0.f, 0.f, 0.f};

  const int rowin = w * 8 + (l >> 3);    // staging row within 64-row group
  const int cslot = (l & 7) ^ (l >> 3);  // pre-swizzled global k-slot
  int koff[2];
#pragma unroll
  for (int ks = 0; ks < 2; ++ks)
    koff[ks] = (l & 15) * 128 + ((ks * 4 + (l >> 4)) ^ (l & 7)) * 16;

  const size_t abase = (size_t)bm * 256 * 4096;
  const size_t bbase = (size_t)bn * 256 * 4096;

  auto stage = [&](int kt, int c) {
    const unsigned short* mat = (c < 2) ? A : B;
    size_t gbase = (c < 2) ? abase : bbase;
    int half = c & 1;
    char* ldst = lds + (kt & 1) * 65536 + ((c < 2) ? 0 : 32768) + half * 16384 + w * 1024;
#pragma unroll
    for (int i = 0; i < 2; ++i) {
      int r = half * 128 + i * 64 + rowin;
      async16(mat + gbase + (size_t)r * 4096 + kt * 64 + cslot * 8, ldst + i * 8192);
    }
  };

  // prologue: tiles 0 and 1 fully staged (8 + 8 loads); tile 0 landed
#pragma unroll
  for (int c = 0; c < 4; ++c) stage(0, c);
#pragma unroll
  for (int c = 0; c < 4; ++c) stage(1, c);
  asm volatile("s_waitcnt vmcnt(8)" ::: "memory");
  BARRIER();

  for (int tt = 0; tt < 62; tt += 2) {
    TILE_BODY(tt, 0, 0);
    TILE_BODY(tt + 1, 1, 0);
  }
  TILE_BODY(62, 0, 1);
  TILE_BODY(63, 1, 2);

#undef TILE_BODY
#undef MFQ

  // C/D layout (m89-verified): col = lane&15, row = (lane>>4)*4 + reg
  int r0 = (l >> 4) * 4;
#pragma unroll
  for (int mi = 0; mi < 8; ++mi) {
    size_t row = (size_t)(bm * 256 + wm + mi * 16 + r0);
#pragma unroll
    for (int ni = 0; ni < 4; ++ni) {
      int col = bn * 256 + wn + ni * 16 + (l & 15);
#pragma unroll
      for (int r = 0; r < 4; ++r)
        C[(row + r) * 4096 + col] = acc[mi][ni][r];
    }
  }
}

// ---------------- fallback (no workspace): fp32 register-blocked ----------------
__global__ __launch_bounds__(256) void fallback_kern(const float* __restrict__ x,
                                                     const float* __restrict__ W,
                                                     float* __restrict__ out) {
  int bi = blockIdx.x & 63;
  int bb = blockIdx.x >> 6;
  int t = threadIdx.x;
  int m = t & 63;
  int cg = t >> 6;
  __shared__ float xs[64][65];
  __shared__ float ws[64];
  float acc[16];
#pragma unroll
  for (int e = 0; e < 16; ++e) acc[e] = 0.f;
  for (int j = 0; j < 64; ++j) {
    __syncthreads();
#pragma unroll
    for (int r = 0; r < 16; ++r) {
      int idx = t + 256 * r;
      int rr = idx >> 6, cc = idx & 63;
      xs[rr][cc] = x[(size_t)(bb * 64 + rr) * 4096 + j * 64 + cc];
    }
    if (t < 64) ws[t] = W[((size_t)(bi * 64 + j)) * 64 + t];
    __syncthreads();
    float xr[64];
#pragma unroll
    for (int e = 0; e < 64; ++e) xr[e] = xs[m][(cg * 16 + e) & 63];
#pragma unroll
    for (int mm = 0; mm < 64; ++mm) {
      float wv = ws[mm];
#pragma unroll
      for (int cc2 = 0; cc2 < 16; ++cc2)
        acc[cc2] = __builtin_fmaf(xr[(cc2 - mm) & 63], wv, acc[cc2]);
    }
  }
  float* dst = out + (size_t)(bb * 64 + m) * 4096 + bi * 64 + cg * 16;
#pragma unroll
  for (int cc2 = 0; cc2 < 16; ++cc2) dst[cc2] = acc[cc2];
}

extern "C" void kernel_launch(void* const* d_in, const int* in_sizes, int n_in,
                              void* d_out, int out_size, void* d_ws, size_t ws_size,
                              hipStream_t stream) {
  const float* x = (const float*)d_in[0];
  const float* W = (const float*)d_in[1];
  float* out = (float*)d_out;
  const size_t need = (size_t)2 * 4096 * 4096 * sizeof(unsigned short);  // 64 MB
  if (ws_size >= need) {
    unsigned short* xb = (unsigned short*)d_ws;
    unsigned short* Mb = xb + (size_t)4096 * 4096;
    cvt_x_kern<<<dim3(8192), dim3(256), 0, stream>>>(x, xb);
    expand_w_kern<<<dim3(4096), dim3(64), 0, stream>>>(W, Mb);
    gemm8<<<dim3(256), dim3(512), 0, stream>>>(xb, Mb, out);
  } else {
    fallback_kern<<<dim3(4096), dim3(256), 0, stream>>>(x, W, out);
  }
}